// Round 1
// baseline (327.344 us; speedup 1.0000x reference)
//
#include <hip/hip_runtime.h>

// PQHead forward: out[b, m*6+d] = codebooks[m, argmax_k dot(x[b,m,:], cb[m,k,:]), d]
// (straight-through estimator: forward value of quant is exactly `discrete`)

#define BATCH 32768
#define DIM   768
#define M_SUB 128
#define K_CB  32
#define D_SUB 6
#define K_HALF 16      // k-split by 2: each lane owns 16 codes
#define B_PER_BLOCK 32

__global__ __launch_bounds__(256, 3)
void pq_head_kernel(const float* __restrict__ x,
                    const float* __restrict__ cb,
                    float* __restrict__ out) {
    const int t  = threadIdx.x;
    const int kh = t & 1;        // which half of the 32 codes
    const int m  = t >> 1;       // subspace 0..127
    const int b0 = blockIdx.x * B_PER_BLOCK;

    // Preload this lane's 16 codebook rows (16 x 6 = 96 floats) into registers.
    // Base offset (m*32 + kh*16)*6 floats = multiple of 96 floats = 384 B -> 16B aligned.
    float c[K_HALF * D_SUB];
    {
        const float4* cb4 = reinterpret_cast<const float4*>(
            cb + ((size_t)m * K_CB + (size_t)kh * K_HALF) * D_SUB);
        #pragma unroll
        for (int i = 0; i < (K_HALF * D_SUB) / 4; ++i) {
            float4 v = cb4[i];
            c[4*i+0] = v.x; c[4*i+1] = v.y; c[4*i+2] = v.z; c[4*i+3] = v.w;
        }
    }

    const float* xrow = x   + (size_t)b0 * DIM + (size_t)m * D_SUB;
    float*       orow = out + (size_t)b0 * DIM + (size_t)m * D_SUB;

    for (int bi = 0; bi < B_PER_BLOCK; ++bi) {
        // Load the 6-float subvector (8B aligned -> 3x dwordx2)
        const float2* xp = reinterpret_cast<const float2*>(xrow);
        float2 a0 = xp[0], a1 = xp[1], a2 = xp[2];
        float xv[D_SUB] = {a0.x, a0.y, a1.x, a1.y, a2.x, a2.y};

        // fp32 dots over my 16 codes, tracking top-2 values + argmax (first-wins)
        float best1 = -3.402823466e+38f;
        float best2 = -3.402823466e+38f;
        int   kloc  = 0;
        #pragma unroll
        for (int j = 0; j < K_HALF; ++j) {
            float d = c[j*D_SUB + 0] * xv[0];
            #pragma unroll
            for (int e = 1; e < D_SUB; ++e)
                d = fmaf(c[j*D_SUB + e], xv[e], d);
            bool gt = d > best1;
            best2 = gt ? best1 : (d > best2 ? d : best2);
            kloc  = gt ? j     : kloc;
            best1 = gt ? d     : best1;
        }

        // Merge across the lane pair (lanes 2j / 2j+1 share (b,m), split k)
        float ob1 = __shfl_xor(best1, 1);
        float ob2 = __shfl_xor(best2, 1);
        int   okl = __shfl_xor(kloc,  1);
        int   kg  = kh * K_HALF + kloc;          // my global code id
        int   okg = (kh ^ 1) * K_HALF + okl;     // partner's global code id

        int kw;
        float g1;
        if (ob1 > best1)      { g1 = ob1;   kw = okg; }
        else if (best1 > ob1) { g1 = best1; kw = kg;  }
        else                  { g1 = best1; kw = (kg < okg) ? kg : okg; } // tie -> first index
        float g2 = fmaxf(fminf(best1, ob1), fmaxf(best2, ob2));

        // Near-tie: fp32 rounding could flip argmax vs the reference.
        // Recompute in fp64 (exact-for-practical-purposes) for this rare case.
        if (g1 - g2 < 1e-5f) {
            double xd[D_SUB];
            #pragma unroll
            for (int e = 0; e < D_SUB; ++e) xd[e] = (double)xv[e];
            double db = -1e300;
            int    dk = 0;
            #pragma unroll
            for (int j = 0; j < K_HALF; ++j) {
                double s = (double)c[j*D_SUB + 0] * xd[0];
                #pragma unroll
                for (int e = 1; e < D_SUB; ++e)
                    s = fma((double)c[j*D_SUB + e], xd[e], s);
                if (s > db) { db = s; dk = j; }
            }
            double odb = __shfl_xor(db, 1);
            int    odk = __shfl_xor(dk, 1);
            int dkg  = kh * K_HALF + dk;
            int odkg = (kh ^ 1) * K_HALF + odk;
            if (odb > db)      kw = odkg;
            else if (db > odb) kw = dkg;
            else               kw = (dkg < odkg) ? dkg : odkg;
        }

        // Gather winner row from L2 and write: even lane -> d 0..2, odd lane -> d 3..5
        const float* src = cb + ((size_t)m * K_CB + (size_t)kw) * D_SUB + kh * 3;
        float*       dst = orow + kh * 3;
        dst[0] = src[0];
        dst[1] = src[1];
        dst[2] = src[2];

        xrow += DIM;
        orow += DIM;
    }
}

extern "C" void kernel_launch(void* const* d_in, const int* in_sizes, int n_in,
                              void* d_out, int out_size, void* d_ws, size_t ws_size,
                              hipStream_t stream) {
    const float* x  = (const float*)d_in[0];   // (32768, 768) fp32
    const float* cb = (const float*)d_in[1];   // (128, 32, 6) fp32
    float* out = (float*)d_out;                // (32768, 768) fp32

    dim3 grid(BATCH / B_PER_BLOCK);  // 1024 blocks
    dim3 block(256);                 // 128 m x 2 k-halves
    hipLaunchKernelGGL(pq_head_kernel, grid, block, 0, stream, x, cb, out);
}

// Round 2
// 296.003 us; speedup vs baseline: 1.1059x; 1.1059x over previous
//
#include <hip/hip_runtime.h>

// PQHead forward: out[b, m*6+d] = codebooks[m, argmax_k dot(x[b,m,:], cb[m,k,:]), d]
// (straight-through estimator: forward value of quant is exactly `discrete`)
//
// R2 design: thread = (m, k-quarter). 8 codes * 6 = 48 cb floats in registers
// (fits under 128-VGPR cap -> allocator keeps them resident, unlike R1's 96).
// NB=4 rows batched per stage for memory-level parallelism. float2 stores.

#define BATCH 32768
#define DIM   768
#define M_SUB 128
#define K_CB  32
#define D_SUB 6
#define KQ    4        // k split 4 ways
#define KPT   8        // codes per thread
#define BROWS 16       // rows per block
#define NB    4        // rows in flight per pipeline stage

__global__ __launch_bounds__(256, 4)
void pq_head_kernel(const float* __restrict__ x,
                    const float* __restrict__ cb,
                    float* __restrict__ out) {
    const int t  = threadIdx.x;
    const int kq = t & 3;                         // k-quarter 0..3
    const int m  = (int)blockIdx.y * 64 + (t >> 2); // subspace 0..127
    const int b0 = blockIdx.x * BROWS;

    // Preload this lane's 8 codebook rows (48 floats = 12 float4, 192B-aligned base).
    float c[KPT * D_SUB];
    {
        const float4* cb4 = reinterpret_cast<const float4*>(
            cb + ((size_t)m * K_CB + (size_t)kq * KPT) * D_SUB);
        #pragma unroll
        for (int i = 0; i < (KPT * D_SUB) / 4; ++i) {
            float4 v = cb4[i];
            c[4*i+0] = v.x; c[4*i+1] = v.y; c[4*i+2] = v.z; c[4*i+3] = v.w;
        }
    }

    const float* xbase = x   + (size_t)b0 * DIM + (size_t)m * D_SUB;
    float*       obase = out + (size_t)b0 * DIM + (size_t)m * D_SUB;

    for (int bb = 0; bb < BROWS; bb += NB) {
        // ---- stage 1: NB independent x loads (3 x dwordx2 each) ----
        float xv[NB][D_SUB];
        #pragma unroll
        for (int n = 0; n < NB; ++n) {
            const float2* xp = reinterpret_cast<const float2*>(
                xbase + (size_t)(bb + n) * DIM);
            float2 a0 = xp[0], a1 = xp[1], a2 = xp[2];
            xv[n][0] = a0.x; xv[n][1] = a0.y; xv[n][2] = a1.x;
            xv[n][3] = a1.y; xv[n][4] = a2.x; xv[n][5] = a2.y;
        }

        // ---- stage 2: NB winner computations ----
        int kw[NB];
        #pragma unroll
        for (int n = 0; n < NB; ++n) {
            float best1 = -3.402823466e+38f;
            float best2 = -3.402823466e+38f;
            int   kg    = kq * KPT;
            #pragma unroll
            for (int j = 0; j < KPT; ++j) {
                float d = c[j*D_SUB + 0] * xv[n][0];
                #pragma unroll
                for (int e = 1; e < D_SUB; ++e)
                    d = fmaf(c[j*D_SUB + e], xv[n][e], d);
                bool gt = d > best1;                       // strict > => first index wins
                best2 = gt ? best1 : fmaxf(best2, d);
                kg    = gt ? (kq * KPT + j) : kg;
                best1 = gt ? d : best1;
            }

            // butterfly merge across the quad (lanes 4i..4i+3 share (b,m))
            #pragma unroll
            for (int s = 1; s <= 2; s <<= 1) {
                float o1 = __shfl_xor(best1, s);
                float o2 = __shfl_xor(best2, s);
                int   ok = __shfl_xor(kg,    s);
                bool take = (o1 > best1) || (o1 == best1 && ok < kg);
                float nb2 = fmaxf(fminf(best1, o1), fmaxf(best2, o2));
                kg    = take ? ok : kg;
                best1 = fmaxf(best1, o1);
                best2 = nb2;
            }

            // Near-tie: fp32 rounding could flip argmax vs the numpy reference.
            // Recompute in fp64 (quad-uniform branch, ~0.1% of tasks).
            if (best1 - best2 < 1e-5f) {
                double db  = -1e300;
                int    dkg = kq * KPT;
                #pragma unroll
                for (int j = 0; j < KPT; ++j) {
                    double sAcc = (double)c[j*D_SUB + 0] * (double)xv[n][0];
                    #pragma unroll
                    for (int e = 1; e < D_SUB; ++e)
                        sAcc = fma((double)c[j*D_SUB + e], (double)xv[n][e], sAcc);
                    if (sAcc > db) { db = sAcc; dkg = kq * KPT + j; }
                }
                #pragma unroll
                for (int s = 1; s <= 2; s <<= 1) {
                    double od  = __shfl_xor(db,  s);
                    int    odk = __shfl_xor(dkg, s);
                    if (od > db || (od == db && odk < dkg)) { db = od; dkg = odk; }
                }
                kg = dkg;
            }
            kw[n] = kg;
        }

        // ---- stage 3: NB independent winner-row gathers (L2-hot cb) ----
        float2 g[NB];
        #pragma unroll
        for (int n = 0; n < NB; ++n) {
            if (kq < 3) {
                const float2* src = reinterpret_cast<const float2*>(
                    cb + ((size_t)m * K_CB + (size_t)kw[n]) * D_SUB) + kq;
                g[n] = *src;
            }
        }

        // ---- stage 4: NB float2 stores (quad lanes 0..2 cover the 6 floats) ----
        #pragma unroll
        for (int n = 0; n < NB; ++n) {
            if (kq < 3) {
                float2* dst = reinterpret_cast<float2*>(
                    obase + (size_t)(bb + n) * DIM) + kq;
                *dst = g[n];
            }
        }
    }
}

extern "C" void kernel_launch(void* const* d_in, const int* in_sizes, int n_in,
                              void* d_out, int out_size, void* d_ws, size_t ws_size,
                              hipStream_t stream) {
    const float* x  = (const float*)d_in[0];   // (32768, 768) fp32
    const float* cb = (const float*)d_in[1];   // (128, 32, 6) fp32
    float* out = (float*)d_out;                // (32768, 768) fp32

    dim3 grid(BATCH / BROWS, 2);   // 2048 row-groups x 2 m-halves = 4096 blocks
    dim3 block(256);               // 64 m x 4 k-quarters
    hipLaunchKernelGGL(pq_head_kernel, grid, block, 0, stream, x, cb, out);
}

// Round 3
// 248.201 us; speedup vs baseline: 1.3189x; 1.1926x over previous
//
#include <hip/hip_runtime.h>

// PQHead forward: out[b, m*6+d] = codebooks[m, argmax_k dot(x[b,m,:], cb[m,k,:]), d]
// (straight-through estimator: forward value of quant is exactly `discrete`)
//
// R3: latency fix. x is staged through LDS (8 rows x 1536 B half-rows,
// coalesced float4), with register prefetch of stage s+1 issued before the
// compute of stage s — consumer (ds_write) is across a barrier in the next
// iteration, so the compiler cannot sink the loads. Thread = (m, k-quarter),
// c[48] register-resident (R2 evidence: VGPR=64 => c was resident).

#define BATCH 32768
#define DIM   768
#define K_CB  32
#define D_SUB 6
#define KPT   8                // codes per thread (k split 4 ways)
#define BROWS 32               // rows per block
#define RSTG  8                // rows per LDS stage
#define HALFF 384              // floats per half row (64 m * 6)
#define STGF  (RSTG*HALFF)     // 3072 floats = 12 KiB per stage

__global__ __launch_bounds__(256)
void pq_head_kernel(const float* __restrict__ x,
                    const float* __restrict__ cb,
                    float* __restrict__ out) {
    __shared__ float xs[STGF];

    const int t     = threadIdx.x;
    const int kq    = t & 3;        // k-quarter
    const int mloc  = t >> 2;       // 0..63
    const int mhalf = blockIdx.y;   // 0/1
    const int m     = mhalf * 64 + mloc;
    const int b0    = blockIdx.x * BROWS;

    // This lane's 8 codebook rows (48 floats), 192-B aligned base -> 12 float4.
    float c[KPT * D_SUB];
    {
        const float4* cb4 = reinterpret_cast<const float4*>(
            cb + ((size_t)m * K_CB + (size_t)kq * KPT) * D_SUB);
        #pragma unroll
        for (int i = 0; i < 12; ++i) {
            float4 v = cb4[i];
            c[4*i+0]=v.x; c[4*i+1]=v.y; c[4*i+2]=v.z; c[4*i+3]=v.w;
        }
    }

    const float* xh = x   + (size_t)mhalf * HALFF;  // half-row base
    float*       oh = out + (size_t)mhalf * HALFF;

    // Prefetch stage 0: 3 x float4 per thread, fully coalesced.
    float4 pf[3];
    #pragma unroll
    for (int i = 0; i < 3; ++i) {
        int f   = (i * 256 + t) * 4;      // float index within stage (< 3072)
        int r   = f / HALFF;              // 0..7
        int col = f - r * HALFF;
        pf[i] = *reinterpret_cast<const float4*>(xh + (size_t)(b0 + r) * DIM + col);
    }

    const int NSTG = BROWS / RSTG;
    for (int s = 0; s < NSTG; ++s) {
        __syncthreads();                              // readers of prev stage done
        #pragma unroll
        for (int i = 0; i < 3; ++i)
            *reinterpret_cast<float4*>(&xs[(i * 256 + t) * 4]) = pf[i];
        __syncthreads();

        if (s + 1 < NSTG) {                           // prefetch next stage NOW;
            int rb = b0 + (s + 1) * RSTG;             // consumer is past a barrier
            #pragma unroll
            for (int i = 0; i < 3; ++i) {
                int f   = (i * 256 + t) * 4;
                int r   = f / HALFF;
                int col = f - r * HALFF;
                pf[i] = *reinterpret_cast<const float4*>(xh + (size_t)(rb + r) * DIM + col);
            }
        }

        #pragma unroll
        for (int r = 0; r < RSTG; ++r) {
            int b = b0 + s * RSTG + r;
            const float* xr = &xs[r * HALFF + mloc * D_SUB];
            float2 x01 = *reinterpret_cast<const float2*>(xr);
            float2 x23 = *reinterpret_cast<const float2*>(xr + 2);
            float2 x45 = *reinterpret_cast<const float2*>(xr + 4);
            float xv[6] = {x01.x, x01.y, x23.x, x23.y, x45.x, x45.y};

            // fp32 top-2 + argmax over my 8 codes (strict > => first index wins)
            float best1 = -3.402823466e+38f;
            float best2 = -3.402823466e+38f;
            int   kg    = kq * KPT;
            #pragma unroll
            for (int j = 0; j < KPT; ++j) {
                float d = c[j*6+0] * xv[0];
                #pragma unroll
                for (int e = 1; e < 6; ++e) d = fmaf(c[j*6+e], xv[e], d);
                bool gt = d > best1;
                best2 = gt ? best1 : fmaxf(best2, d);
                kg    = gt ? (kq * KPT + j) : kg;
                best1 = gt ? d : best1;
            }

            // butterfly merge across the quad
            #pragma unroll
            for (int sft = 1; sft <= 2; sft <<= 1) {
                float o1 = __shfl_xor(best1, sft);
                float o2 = __shfl_xor(best2, sft);
                int   ok = __shfl_xor(kg,    sft);
                bool take = (o1 > best1) || (o1 == best1 && ok < kg);
                best2 = fmaxf(fminf(best1, o1), fmaxf(best2, o2));
                kg    = take ? ok : kg;
                best1 = fmaxf(best1, o1);
            }

            // Near-tie (quad-uniform, ~0.1%): exact fp64 argmax from global cb.
            if (best1 - best2 < 1e-5f) {
                const float* crow = cb + (size_t)m * K_CB * D_SUB;
                double db = -1e300; int dkg = 0;
                for (int k2 = 0; k2 < K_CB; ++k2) {
                    double sa = 0.0;
                    for (int e = 0; e < 6; ++e)
                        sa = fma((double)crow[k2*6+e], (double)xv[e], sa);
                    if (sa > db) { db = sa; dkg = k2; }
                }
                kg = dkg;
            }

            // Gather winner row (cb is 96 KB, L1/L2-hot) and store float2.
            // No consumer downstream -> latency tolerable, overlapped across rows.
            if (kq < 3) {
                float2 g = *(reinterpret_cast<const float2*>(
                    cb + ((size_t)m * K_CB + (size_t)kg) * D_SUB) + kq);
                *(reinterpret_cast<float2*>(oh + (size_t)b * DIM) + (mloc * 3 + kq)) = g;
            }
        }
    }
}

extern "C" void kernel_launch(void* const* d_in, const int* in_sizes, int n_in,
                              void* d_out, int out_size, void* d_ws, size_t ws_size,
                              hipStream_t stream) {
    const float* x  = (const float*)d_in[0];   // (32768, 768) fp32
    const float* cb = (const float*)d_in[1];   // (128, 32, 6) fp32
    float* out = (float*)d_out;                // (32768, 768) fp32

    dim3 grid(BATCH / BROWS, 2);   // 1024 x 2 = 2048 blocks
    dim3 block(256);               // 64 m x 4 k-quarters
    hipLaunchKernelGGL(pq_head_kernel, grid, block, 0, stream, x, cb, out);
}